// Round 5
// baseline (372.529 us; speedup 1.0000x reference)
//
#include <hip/hip_runtime.h>
#include <math.h>

#define EPSF 1e-10f

typedef int   vi4 __attribute__((ext_vector_type(4)));
typedef float vf4 __attribute__((ext_vector_type(4)));
typedef int   vi2 __attribute__((ext_vector_type(2)));

struct Pair { float term; int parent; };  // merged 8 B record: one load per walk step

__device__ __forceinline__ unsigned short f32_to_bf16(float f) {
    unsigned int u = __float_as_uint(f);
    // round-to-nearest-even (inputs are finite, no NaN handling needed)
    u += 0x7fffu + ((u >> 16) & 1u);
    return (unsigned short)(u >> 16);
}
__device__ __forceinline__ float bf16_to_f32(unsigned short h) {
    return __uint_as_float(((unsigned int)h) << 16);
}

// Kernel 1: feature transform + linear + sigmoid -> pairs[i] = {diff[i]*score, parent[i]}
// attr staged via coalesced float4 -> LDS; row read stride 15 (odd) = conflict-free.
// Fast transcendentals: rel err ~1e-6, invisible under bf16 table quantization.
__global__ __launch_bounds__(256) void term_kernel(
    const float* __restrict__ diff,
    const float* __restrict__ attr,    // N x 15 row-major
    const float* __restrict__ weight,  // 17
    const float* __restrict__ bias,    // 1
    const int*   __restrict__ parent,
    Pair* __restrict__ pairs, int N)
{
    __shared__ float sa[256 * 15];
    int tid = threadIdx.x;
    long long fbase = (long long)blockIdx.x * (256 * 15);   // float index of block's first row
    long long totalf = (long long)N * 15;
    const vf4* a4 = (const vf4*)(attr + fbase);             // fbase % 4 == 0
#pragma unroll
    for (int t = tid, k = 0; k < 4; ++k, t += 256) {        // 960 float4 / block
        if (t < 960 && fbase + (long long)t * 4 < totalf) {
            vf4 v = a4[t];
            *(vf4*)&sa[t * 4] = v;
        }
    }
    __syncthreads();

    int i = blockIdx.x * 256 + tid;
    if (i >= N) return;
    const float* f = &sa[tid * 15];

    float acc = bias[0];
#pragma unroll
    for (int k = 0; k < 5; ++k) acc += f[k] * weight[k];          // raw 0..4
#pragma unroll
    for (int k = 0; k < 9; ++k)                                   // log(|attr 6..14|+eps)
        acc += __logf(fabsf(f[6 + k]) + EPSF) * weight[5 + k];
    acc += __fdividef(sqrtf(f[7]), sqrtf(f[6]) + EPSF) * weight[14];  // lshape
    acc += __cosf(f[5]) * weight[15];
    acc += __sinf(f[5]) * weight[16];

    float sig = 1.0f / (1.0f + __expf(-acc));
    Pair pr; pr.term = diff[i] * sig; pr.parent = parent[i];
    pairs[i] = pr;
}

// Kernel 2 (launched 3x with [lo,hi) ranges): walk ancestors while j>=lo using
// merged pairs; below lo the prefix sum is already in nv[] from an earlier phase.
// Plain (L1/L2-allocating) loads: hot low-index ancestor records are re-read by
// many walkers — nt cost +93 us (r2); sc0 was neutral on random gathers (r4).
__global__ __launch_bounds__(256) void chain_phase(
    const Pair* __restrict__ pairs,
    float* __restrict__ nv,            // f32 node_vals (read by later phases)
    unsigned short* __restrict__ nvb,  // bf16 copy (read by gather; 4 MB fits per-XCD L2)
    int lo, int hi)
{
    int i = lo + blockIdx.x * blockDim.x + threadIdx.x;
    if (i >= hi) return;
    float s = 0.0f;
    int j = i;
    const vi2* p2 = (const vi2*)pairs;
    while (j >= lo) {            // lo==0: walks to root (parent of root = -1 < 0)
        vi2 pr = p2[j];
        s += __int_as_float(pr.x);
        j = pr.y;
    }
    if (j >= 0) s += nv[j];      // prefix sum of first ancestor below lo
    nv[i] = s;
    __builtin_nontemporal_store(f32_to_bf16(s), nvb + i);
}

// Kernel 3 (launched 4x on quarter ranges for per-phase duration attribution in
// rocprof top-k; also keeps the table L2-warm across consecutive dispatches).
// Gather rate is miss-queue x L2-latency bound (~0.28 req/cy/CU measured; MLP,
// nt, sc0 all failed to move it) — request count is the only lever, and it's
// fixed by the problem. Plain table loads (L2-resident 4 MB); pixel/out streams
// nontemporal so they don't evict the table.
__global__ __launch_bounds__(256) void gather_kernel(
    const unsigned short* __restrict__ nvb,
    const int* __restrict__ pixel_node,
    float* __restrict__ out, long long lo4, long long hi4, long long M)
{
    long long idx = lo4 + (long long)blockIdx.x * blockDim.x + threadIdx.x;
    long long stride = (long long)gridDim.x * blockDim.x;
    const vi4* pn4 = (const vi4*)pixel_node;
    vf4* out4 = (vf4*)out;

    long long t = idx;
    for (; t + 3 * stride < hi4; t += 4 * stride) {
        vi4 p0 = __builtin_nontemporal_load(pn4 + t);
        vi4 p1 = __builtin_nontemporal_load(pn4 + t + stride);
        vi4 p2 = __builtin_nontemporal_load(pn4 + t + 2 * stride);
        vi4 p3 = __builtin_nontemporal_load(pn4 + t + 3 * stride);

        unsigned short g00 = nvb[p0.x], g01 = nvb[p0.y], g02 = nvb[p0.z], g03 = nvb[p0.w];
        unsigned short g10 = nvb[p1.x], g11 = nvb[p1.y], g12 = nvb[p1.z], g13 = nvb[p1.w];
        unsigned short g20 = nvb[p2.x], g21 = nvb[p2.y], g22 = nvb[p2.z], g23 = nvb[p2.w];
        unsigned short g30 = nvb[p3.x], g31 = nvb[p3.y], g32 = nvb[p3.z], g33 = nvb[p3.w];

        vf4 v0, v1, v2, v3;
        v0.x = bf16_to_f32(g00); v0.y = bf16_to_f32(g01);
        v0.z = bf16_to_f32(g02); v0.w = bf16_to_f32(g03);
        v1.x = bf16_to_f32(g10); v1.y = bf16_to_f32(g11);
        v1.z = bf16_to_f32(g12); v1.w = bf16_to_f32(g13);
        v2.x = bf16_to_f32(g20); v2.y = bf16_to_f32(g21);
        v2.z = bf16_to_f32(g22); v2.w = bf16_to_f32(g23);
        v3.x = bf16_to_f32(g30); v3.y = bf16_to_f32(g31);
        v3.z = bf16_to_f32(g32); v3.w = bf16_to_f32(g33);

        __builtin_nontemporal_store(v0, out4 + t);
        __builtin_nontemporal_store(v1, out4 + t + stride);
        __builtin_nontemporal_store(v2, out4 + t + 2 * stride);
        __builtin_nontemporal_store(v3, out4 + t + 3 * stride);
    }
    for (; t < hi4; t += stride) {
        vi4 p = __builtin_nontemporal_load(pn4 + t);
        vf4 v;
        v.x = bf16_to_f32(nvb[p.x]);
        v.y = bf16_to_f32(nvb[p.y]);
        v.z = bf16_to_f32(nvb[p.z]);
        v.w = bf16_to_f32(nvb[p.w]);
        __builtin_nontemporal_store(v, out4 + t);
    }
    // global scalar tail (M % 4 != 0), handled by the dispatch owning the end
    if (hi4 == (M >> 2)) {
        long long base = (M >> 2) << 2;
        for (long long s = base + (idx - lo4); s < M; s += stride)
            out[s] = bf16_to_f32(nvb[pixel_node[s]]);
    }
}

extern "C" void kernel_launch(void* const* d_in, const int* in_sizes, int n_in,
                              void* d_out, int out_size, void* d_ws, size_t ws_size,
                              hipStream_t stream) {
    const float* diff   = (const float*)d_in[0];
    const float* attr   = (const float*)d_in[1];
    const float* weight = (const float*)d_in[2];
    const float* bias   = (const float*)d_in[3];
    const int*   parent = (const int*)d_in[4];
    const int*   pixel  = (const int*)d_in[5];
    float* out = (float*)d_out;

    int N = in_sizes[0];
    Pair*           pairs = (Pair*)d_ws;                      // N * 8 B
    float*          nv    = (float*)(pairs + N);              // N * 4 B
    unsigned short* nvb   = (unsigned short*)(nv + N);        // N * 2 B

    int T1 = N < (1 << 16) ? N : (1 << 16);   // 64K: walk region 512 KB, L2-hot
    int T2 = N < (1 << 20) ? N : (1 << 20);   // 1M

    int blocks = (N + 255) / 256;
    term_kernel<<<blocks, 256, 0, stream>>>(diff, attr, weight, bias, parent, pairs, N);

    chain_phase<<<(T1 + 255) / 256, 256, 0, stream>>>(pairs, nv, nvb, 0, T1);
    if (T2 > T1)
        chain_phase<<<(T2 - T1 + 255) / 256, 256, 0, stream>>>(pairs, nv, nvb, T1, T2);
    if (N > T2)
        chain_phase<<<(N - T2 + 255) / 256, 256, 0, stream>>>(pairs, nv, nvb, T2, N);

    long long M  = (long long)out_size;
    long long M4 = M >> 2;
    long long q  = (M4 + 3) / 4;
    for (int k = 0; k < 4; ++k) {
        long long lo4 = (long long)k * q;
        long long hi4 = (k + 1) * q < M4 ? (k + 1) * q : M4;
        if (lo4 < hi4 || (k == 3 && (M & 3)))
            gather_kernel<<<4096, 256, 0, stream>>>(nvb, pixel, out, lo4, hi4, M);
    }
}

// Round 7
// 364.050 us; speedup vs baseline: 1.0233x; 1.0233x over previous
//
#include <hip/hip_runtime.h>
#include <math.h>

#define EPSF 1e-10f

typedef int   vi4 __attribute__((ext_vector_type(4)));
typedef float vf4 __attribute__((ext_vector_type(4)));
typedef int   vi2 __attribute__((ext_vector_type(2)));

struct Pair { float term; int parent; };  // merged 8 B record: one load per walk step

__device__ __forceinline__ unsigned short f32_to_bf16(float f) {
    unsigned int u = __float_as_uint(f);
    // round-to-nearest-even (inputs are finite, no NaN handling needed)
    u += 0x7fffu + ((u >> 16) & 1u);
    return (unsigned short)(u >> 16);
}
__device__ __forceinline__ float bf16_to_f32(unsigned short h) {
    return __uint_as_float(((unsigned int)h) << 16);
}

// Kernel 1: feature transform + linear + sigmoid -> pairs[i] = {diff[i]*score, parent[i]}
// attr staged via coalesced float4 -> LDS; row read stride 15 (odd) = conflict-free.
// Fast transcendentals: rel err ~1e-6, invisible under bf16 table quantization.
__global__ __launch_bounds__(256) void term_kernel(
    const float* __restrict__ diff,
    const float* __restrict__ attr,    // N x 15 row-major
    const float* __restrict__ weight,  // 17
    const float* __restrict__ bias,    // 1
    const int*   __restrict__ parent,
    Pair* __restrict__ pairs, int N)
{
    __shared__ float sa[256 * 15];
    int tid = threadIdx.x;
    long long fbase = (long long)blockIdx.x * (256 * 15);   // float index of block's first row
    long long totalf = (long long)N * 15;
    const vf4* a4 = (const vf4*)(attr + fbase);             // fbase % 4 == 0
#pragma unroll
    for (int t = tid, k = 0; k < 4; ++k, t += 256) {        // 960 float4 / block
        if (t < 960 && fbase + (long long)t * 4 < totalf) {
            vf4 v = a4[t];
            *(vf4*)&sa[t * 4] = v;
        }
    }
    __syncthreads();

    int i = blockIdx.x * 256 + tid;
    if (i >= N) return;
    const float* f = &sa[tid * 15];

    float acc = bias[0];
#pragma unroll
    for (int k = 0; k < 5; ++k) acc += f[k] * weight[k];          // raw 0..4
#pragma unroll
    for (int k = 0; k < 9; ++k)                                   // log(|attr 6..14|+eps)
        acc += __logf(fabsf(f[6 + k]) + EPSF) * weight[5 + k];
    acc += __fdividef(sqrtf(f[7]), sqrtf(f[6]) + EPSF) * weight[14];  // lshape
    acc += __cosf(f[5]) * weight[15];
    acc += __sinf(f[5]) * weight[16];

    float sig = 1.0f / (1.0f + __expf(-acc));
    Pair pr; pr.term = diff[i] * sig; pr.parent = parent[i];
    pairs[i] = pr;
}

// Kernel 2 (launched per phase [lo,hi)): walk ancestors while j>=lo using merged
// pairs; below lo the prefix sum is already in nv[] from an earlier phase.
// PHASE SIZING (round-6 theory): the walk's random reads are confined to
// pairs[lo..hi) (parent[j] < j and walk stops below lo). Keep that slice
// <= 4 MB (512K nodes) so it fits a per-XCD L2 — every XCD walks the same
// slice and caches its own copy. Previous 1M-node phases spanned 8 MB ->
// random-line HBM misses dominated chain time.
// Loads stay plain/L2-allocating: nt cost +93 us (r2); sc0 neutral (r4).
__global__ __launch_bounds__(256) void chain_phase(
    const Pair* __restrict__ pairs,
    float* __restrict__ nv,            // f32 node_vals (read by later phases)
    unsigned short* __restrict__ nvb,  // bf16 copy (read by gather; 4 MB fits per-XCD L2)
    int lo, int hi)
{
    int i = lo + blockIdx.x * blockDim.x + threadIdx.x;
    if (i >= hi) return;
    float s = 0.0f;
    int j = i;
    const vi2* p2 = (const vi2*)pairs;
    while (j >= lo) {            // lo==0: walks to root (parent of root = -1 < 0)
        vi2 pr = p2[j];
        s += __int_as_float(pr.x);
        j = pr.y;
    }
    if (j >= 0) s += nv[j];      // prefix sum of first ancestor below lo (f32: no extra quantization)
    nv[i] = s;
    __builtin_nontemporal_store(f32_to_bf16(s), nvb + i);
}

// Kernel 3: out[p] = bf16->f32(nvb[pixel_node[p]]).
// Gather rate is miss-queue x L2-latency bound (~0.28 req/cy/CU measured; MLP,
// nt, sc0 all failed to move it) — structurally floored. Plain table loads
// (L2-resident 4 MB table); pixel/out streams nontemporal so they don't evict it.
__global__ __launch_bounds__(256) void gather_kernel(
    const unsigned short* __restrict__ nvb,
    const int* __restrict__ pixel_node,
    float* __restrict__ out, long long M)
{
    long long idx = (long long)blockIdx.x * blockDim.x + threadIdx.x;
    long long stride = (long long)gridDim.x * blockDim.x;
    long long M4 = M >> 2;
    const vi4* pn4 = (const vi4*)pixel_node;
    vf4* out4 = (vf4*)out;

    long long t = idx;
    for (; t + 3 * stride < M4; t += 4 * stride) {
        vi4 p0 = __builtin_nontemporal_load(pn4 + t);
        vi4 p1 = __builtin_nontemporal_load(pn4 + t + stride);
        vi4 p2 = __builtin_nontemporal_load(pn4 + t + 2 * stride);
        vi4 p3 = __builtin_nontemporal_load(pn4 + t + 3 * stride);

        unsigned short g00 = nvb[p0.x], g01 = nvb[p0.y], g02 = nvb[p0.z], g03 = nvb[p0.w];
        unsigned short g10 = nvb[p1.x], g11 = nvb[p1.y], g12 = nvb[p1.z], g13 = nvb[p1.w];
        unsigned short g20 = nvb[p2.x], g21 = nvb[p2.y], g22 = nvb[p2.z], g23 = nvb[p2.w];
        unsigned short g30 = nvb[p3.x], g31 = nvb[p3.y], g32 = nvb[p3.z], g33 = nvb[p3.w];

        vf4 v0, v1, v2, v3;
        v0.x = bf16_to_f32(g00); v0.y = bf16_to_f32(g01);
        v0.z = bf16_to_f32(g02); v0.w = bf16_to_f32(g03);
        v1.x = bf16_to_f32(g10); v1.y = bf16_to_f32(g11);
        v1.z = bf16_to_f32(g12); v1.w = bf16_to_f32(g13);
        v2.x = bf16_to_f32(g20); v2.y = bf16_to_f32(g21);
        v2.z = bf16_to_f32(g22); v2.w = bf16_to_f32(g23);
        v3.x = bf16_to_f32(g30); v3.y = bf16_to_f32(g31);
        v3.z = bf16_to_f32(g32); v3.w = bf16_to_f32(g33);

        __builtin_nontemporal_store(v0, out4 + t);
        __builtin_nontemporal_store(v1, out4 + t + stride);
        __builtin_nontemporal_store(v2, out4 + t + 2 * stride);
        __builtin_nontemporal_store(v3, out4 + t + 3 * stride);
    }
    for (; t < M4; t += stride) {
        vi4 p = __builtin_nontemporal_load(pn4 + t);
        vf4 v;
        v.x = bf16_to_f32(nvb[p.x]);
        v.y = bf16_to_f32(nvb[p.y]);
        v.z = bf16_to_f32(nvb[p.z]);
        v.w = bf16_to_f32(nvb[p.w]);
        __builtin_nontemporal_store(v, out4 + t);
    }
    for (long long s = (M4 << 2) + idx; s < M; s += stride)
        out[s] = bf16_to_f32(nvb[pixel_node[s]]);
}

extern "C" void kernel_launch(void* const* d_in, const int* in_sizes, int n_in,
                              void* d_out, int out_size, void* d_ws, size_t ws_size,
                              hipStream_t stream) {
    const float* diff   = (const float*)d_in[0];
    const float* attr   = (const float*)d_in[1];
    const float* weight = (const float*)d_in[2];
    const float* bias   = (const float*)d_in[3];
    const int*   parent = (const int*)d_in[4];
    const int*   pixel  = (const int*)d_in[5];
    float* out = (float*)d_out;

    int N = in_sizes[0];
    Pair*           pairs = (Pair*)d_ws;                      // N * 8 B
    float*          nv    = (float*)(pairs + N);              // N * 4 B
    unsigned short* nvb   = (unsigned short*)(nv + N);        // N * 2 B

    int blocks = (N + 255) / 256;
    term_kernel<<<blocks, 256, 0, stream>>>(diff, attr, weight, bias, parent, pairs, N);

    // Phase boundaries: walk slice of each phase (pairs[lo..hi)) <= 4 MB = 512K
    // nodes, so it stays resident in each XCD's 4 MB L2 during the phase.
    const int NB = 6;
    int bounds[NB] = {0, 1 << 16, 1 << 19, 1 << 20, 3 << 19, 1 << 21};
    int prev = 0;
    for (int b = 1; b < NB; ++b) {
        int lo = prev;
        int hi = bounds[b] < N ? bounds[b] : N;
        if (hi > lo) {
            chain_phase<<<(hi - lo + 255) / 256, 256, 0, stream>>>(pairs, nv, nvb, lo, hi);
            prev = hi;
        }
    }
    if (N > prev)  // N beyond last fixed bound: one final phase
        chain_phase<<<(N - prev + 255) / 256, 256, 0, stream>>>(pairs, nv, nvb, prev, N);

    gather_kernel<<<4096, 256, 0, stream>>>(nvb, pixel, out, (long long)out_size);
}